// Round 1
// baseline (444.164 us; speedup 1.0000x reference)
//
#include <hip/hip_runtime.h>
#include <math.h>

#define BB 32
#define SS 4096
#define HH 256

// ---------------------------------------------------------------------------
// Kernel 1: qq[b][h] = hidden[b] @ W1_w[:,h] + W1_b[h] + W2_b[h]
// (fold both bias terms: energy = tanh(q + k) with k = enc@W2 + W2_b)
// grid = (B), block = 256 (one thread per h)
// ---------------------------------------------------------------------------
__global__ void qq_kernel(const float* __restrict__ hidden,
                          const float* __restrict__ W1_w,
                          const float* __restrict__ W1_b,
                          const float* __restrict__ W2_b,
                          float* __restrict__ qq) {
    __shared__ float hid[HH];
    const int b = blockIdx.x;
    const int h = threadIdx.x;
    hid[h] = hidden[b * HH + h];
    __syncthreads();
    float acc = 0.f;
#pragma unroll 8
    for (int k = 0; k < HH; ++k)
        acc = fmaf(hid[k], W1_w[k * HH + h], acc);
    qq[b * HH + h] = acc + W1_b[h] + W2_b[h];
}

// ---------------------------------------------------------------------------
// Kernel 2: fused score GEMM.
// scores[b][s] = sum_h V_w[h] * tanh(qq[b][h] + (enc[b,s,:] @ W2_w[:,h])) + V_b
// grid = (S/32, B), block = 256. Tile: 32 s-positions x 256 h.
// Thread (sg = t/32, hg = t%32) owns 4 s (sg*4..) x 8 h (hg*8..): acc[4][8].
// K staged in chunks of 32: W2 chunk 32x256 (32 KB) + enc chunk 32x32 (4 KB).
// ---------------------------------------------------------------------------
__global__ __launch_bounds__(256)
void score_kernel(const float* __restrict__ enc,
                  const float* __restrict__ W2_w,
                  const float* __restrict__ qq,
                  const float* __restrict__ V_w,
                  const float* __restrict__ V_b,
                  float* __restrict__ scores) {
    __shared__ float w2s[32][HH];   // [k][h]
    __shared__ float encs[32][32];  // [s][k]

    const int t  = threadIdx.x;
    const int b  = blockIdx.y;
    const int s0 = blockIdx.x * 32;

    const int sg = t >> 5;          // 0..7  -> s_base = sg*4
    const int hg = t & 31;          // 0..31 -> h0 = hg*8
    const int s_base = sg * 4;
    const int h0 = hg * 8;

    float acc[4][8];
#pragma unroll
    for (int si = 0; si < 4; ++si)
#pragma unroll
        for (int j = 0; j < 8; ++j) acc[si][j] = 0.f;

    for (int kc = 0; kc < HH / 32; ++kc) {
        __syncthreads();  // protect LDS from previous chunk's readers
        // stage W2 chunk: rows kc*32 .. kc*32+31, all 256 cols (contiguous copy)
        {
            const float4* wsrc = (const float4*)(W2_w + (size_t)(kc * 32) * HH);
            float4* wdst = (float4*)&w2s[0][0];
#pragma unroll
            for (int i = 0; i < 8; ++i)
                wdst[i * 256 + t] = wsrc[i * 256 + t];
        }
        // stage enc chunk: 32 s-rows x 32 k-cols; thread t loads one float4
        {
            const int row = t >> 3;
            const int c4  = (t & 7) * 4;
            *(float4*)&encs[row][c4] =
                *(const float4*)&enc[(size_t)(b * SS + s0 + row) * HH + kc * 32 + c4];
        }
        __syncthreads();

        // compute: 32 k values
#pragma unroll
        for (int k4 = 0; k4 < 8; ++k4) {
            float ev[4][4];
#pragma unroll
            for (int si = 0; si < 4; ++si)
                *(float4*)ev[si] = *(const float4*)&encs[s_base + si][k4 * 4];
#pragma unroll
            for (int kk = 0; kk < 4; ++kk) {
                const int k = k4 * 4 + kk;
                const float4 wa = *(const float4*)&w2s[k][h0];
                const float4 wb = *(const float4*)&w2s[k][h0 + 4];
                const float w[8] = {wa.x, wa.y, wa.z, wa.w, wb.x, wb.y, wb.z, wb.w};
#pragma unroll
                for (int si = 0; si < 4; ++si) {
                    const float e = ev[si][kk];
#pragma unroll
                    for (int j = 0; j < 8; ++j)
                        acc[si][j] = fmaf(e, w[j], acc[si][j]);
                }
            }
        }
    }

    // epilogue: tanh, dot with V over this thread's 8 h, reduce across 32 lanes
    float qv[8], vv[8];
#pragma unroll
    for (int j = 0; j < 8; ++j) {
        qv[j] = qq[b * HH + h0 + j];
        vv[j] = V_w[h0 + j];
    }
    const float vb = V_b[0];
#pragma unroll
    for (int si = 0; si < 4; ++si) {
        float p = 0.f;
#pragma unroll
        for (int j = 0; j < 8; ++j)
            p = fmaf(vv[j], tanhf(qv[j] + acc[si][j]), p);
        // reduce across the 32 lanes sharing this sg (half-wave)
#pragma unroll
        for (int off = 16; off > 0; off >>= 1)
            p += __shfl_down(p, off, 32);
        if (hg == 0)
            scores[b * SS + s0 + s_base + si] = p + vb;
    }
}

// ---------------------------------------------------------------------------
// Kernel 3: per-b softmax stats: m = max_s score, l = sum_s exp(score - m)
// grid = (B), block = 256
// ---------------------------------------------------------------------------
__global__ void stats_kernel(const float* __restrict__ scores,
                             float* __restrict__ stats) {
    __shared__ float red[256];
    const int b = blockIdx.x;
    const int t = threadIdx.x;
    float m = -INFINITY;
    for (int s = t; s < SS; s += 256) m = fmaxf(m, scores[b * SS + s]);
    red[t] = m;
    __syncthreads();
    for (int off = 128; off > 0; off >>= 1) {
        if (t < off) red[t] = fmaxf(red[t], red[t + off]);
        __syncthreads();
    }
    m = red[0];
    __syncthreads();
    float l = 0.f;
    for (int s = t; s < SS; s += 256) l += expf(scores[b * SS + s] - m);
    red[t] = l;
    __syncthreads();
    for (int off = 128; off > 0; off >>= 1) {
        if (t < off) red[t] += red[t + off];
        __syncthreads();
    }
    if (t == 0) {
        stats[b] = m;
        stats[BB + b] = red[0];
    }
}

// ---------------------------------------------------------------------------
// Kernel 4: weights (to d_out) + partial context per (b, 256-s chunk)
// grid = (16, B), block = 256
// ---------------------------------------------------------------------------
__global__ __launch_bounds__(256)
void ctx_kernel(const float* __restrict__ scores,
                const float* __restrict__ stats,
                const float* __restrict__ enc,
                float* __restrict__ weights_out,
                float* __restrict__ part) {
    __shared__ float w[256];
    const int b = blockIdx.y;
    const int chunk = blockIdx.x;
    const int t = threadIdx.x;
    const int s0 = chunk * 256;

    const float m = stats[b];
    const float linv = 1.f / stats[BB + b];
    const float wv = expf(scores[b * SS + s0 + t] - m) * linv;
    weights_out[b * SS + s0 + t] = wv;
    w[t] = wv;
    __syncthreads();

    float acc = 0.f;
    const float* ep = enc + (size_t)(b * SS + s0) * HH + t;  // column t
#pragma unroll 8
    for (int j = 0; j < 256; ++j)
        acc = fmaf(w[j], ep[(size_t)j * HH], acc);
    part[(b * 16 + chunk) * HH + t] = acc;
}

// ---------------------------------------------------------------------------
// Kernel 5: reduce 16 partials -> context (to d_out)
// grid = (B), block = 256
// ---------------------------------------------------------------------------
__global__ void reduce_kernel(const float* __restrict__ part,
                              float* __restrict__ ctx_out) {
    const int b = blockIdx.x;
    const int h = threadIdx.x;
    float a = 0.f;
#pragma unroll
    for (int c = 0; c < 16; ++c) a += part[(b * 16 + c) * HH + h];
    ctx_out[b * HH + h] = a;
}

// ---------------------------------------------------------------------------
extern "C" void kernel_launch(void* const* d_in, const int* in_sizes, int n_in,
                              void* d_out, int out_size, void* d_ws, size_t ws_size,
                              hipStream_t stream) {
    const float* hidden = (const float*)d_in[0];
    const float* enc    = (const float*)d_in[1];
    const float* W1_w   = (const float*)d_in[2];
    const float* W1_b   = (const float*)d_in[3];
    const float* W2_w   = (const float*)d_in[4];
    const float* W2_b   = (const float*)d_in[5];
    const float* V_w    = (const float*)d_in[6];
    const float* V_b    = (const float*)d_in[7];

    float* out_weights = (float*)d_out;                 // B*S
    float* out_ctx     = (float*)d_out + BB * SS;       // B*H

    float* ws      = (float*)d_ws;
    float* ws_qq   = ws;                                 // B*H    = 8192
    float* ws_sc   = ws + BB * HH;                       // B*S    = 131072
    float* ws_st   = ws_sc + BB * SS;                    // 2*B    = 64
    float* ws_part = ws_st + 2 * BB;                     // B*16*H = 131072

    qq_kernel<<<dim3(BB), dim3(HH), 0, stream>>>(hidden, W1_w, W1_b, W2_b, ws_qq);
    score_kernel<<<dim3(SS / 32, BB), dim3(256), 0, stream>>>(
        enc, W2_w, ws_qq, V_w, V_b, ws_sc);
    stats_kernel<<<dim3(BB), dim3(256), 0, stream>>>(ws_sc, ws_st);
    ctx_kernel<<<dim3(16, BB), dim3(256), 0, stream>>>(
        ws_sc, ws_st, enc, out_weights, ws_part);
    reduce_kernel<<<dim3(BB), dim3(HH), 0, stream>>>(ws_part, out_ctx);
}

// Round 2
// 347.850 us; speedup vs baseline: 1.2769x; 1.2769x over previous
//
#include <hip/hip_runtime.h>
#include <hip/hip_bf16.h>
#include <math.h>

#define BB 32
#define SS 4096
#define HH 256

typedef __bf16 bf16x8 __attribute__((ext_vector_type(8)));
typedef float f32x4 __attribute__((ext_vector_type(4)));

__device__ inline bf16x8 cvt8(const float4& x, const float4& y) {
    union { __hip_bfloat162 p[4]; bf16x8 v; } u;
    u.p[0] = __float22bfloat162_rn(make_float2(x.x, x.y));
    u.p[1] = __float22bfloat162_rn(make_float2(x.z, x.w));
    u.p[2] = __float22bfloat162_rn(make_float2(y.x, y.y));
    u.p[3] = __float22bfloat162_rn(make_float2(y.z, y.w));
    return u.v;
}

// ---------------------------------------------------------------------------
// Prep: W2 (fp32 [k][n]) -> bf16 in MFMA B-fragment swizzled order:
// w2sw[ ((kc*16 + nt)*64 + lane)*8 + j ] = W2[kc*32 + (lane>>4)*8 + j][nt*16 + (lane&15)]
// ---------------------------------------------------------------------------
__global__ void w2_swizzle_kernel(const float* __restrict__ W2_w,
                                  ushort* __restrict__ w2sw) {
    const int i = blockIdx.x * 256 + threadIdx.x;   // 65536 total
    const int j    = i & 7;
    const int lane = (i >> 3) & 63;
    const int nt   = (i >> 9) & 15;
    const int kc   = i >> 13;
    const int k = kc * 32 + ((lane >> 4) & 3) * 8 + j;
    const int n = nt * 16 + (lane & 15);
    __hip_bfloat16 h = __float2bfloat16(W2_w[k * HH + n]);
    w2sw[i] = *(ushort*)&h;
}

// ---------------------------------------------------------------------------
// qq[b][h] = hidden[b] @ W1_w[:,h] + W1_b[h] + W2_b[h]   (fp32, exact)
// ---------------------------------------------------------------------------
__global__ void qq_kernel(const float* __restrict__ hidden,
                          const float* __restrict__ W1_w,
                          const float* __restrict__ W1_b,
                          const float* __restrict__ W2_b,
                          float* __restrict__ qq) {
    __shared__ float hid[HH];
    const int b = blockIdx.x;
    const int h = threadIdx.x;
    hid[h] = hidden[b * HH + h];
    __syncthreads();
    float acc = 0.f;
#pragma unroll 8
    for (int k = 0; k < HH; ++k)
        acc = fmaf(hid[k], W1_w[k * HH + h], acc);
    qq[b * HH + h] = acc + W1_b[h] + W2_b[h];
}

// ---------------------------------------------------------------------------
// MFMA score kernel.
// grid (SS/128, BB), block 256 (4 waves: mw = w&1 over 64-row halves,
// nw = w>>1 over 128-col halves). K-chunk = 32, 8 chunks, W2 chunks
// double-buffered in LDS; enc read fp32 global -> cvt bf16 in registers.
// scores[b][s] = V_b + sum_n V[n] * tanh(qq[b][n] + (enc[b,s,:] @ W2)[n])
// ---------------------------------------------------------------------------
__global__ __launch_bounds__(256, 2)
void score_mfma_kernel(const float* __restrict__ enc,
                       const ushort* __restrict__ w2sw,
                       const float* __restrict__ qq,
                       const float* __restrict__ V_w,
                       const float* __restrict__ V_b,
                       float* __restrict__ scores) {
    __shared__ ushort w2buf[2][8192];   // 2 x 16 KB
    __shared__ float scbuf[128];

    const int t    = threadIdx.x;
    const int b    = blockIdx.y;
    const int s0   = blockIdx.x * 128;
    const int wave = t >> 6;
    const int lane = t & 63;
    const int mw   = wave & 1;
    const int nw   = wave >> 1;
    const int l15  = lane & 15;
    const int quad = lane >> 4;

    f32x4 acc[4][8];
#pragma unroll
    for (int mt = 0; mt < 4; ++mt)
#pragma unroll
        for (int nt = 0; nt < 8; ++nt)
            acc[mt][nt] = (f32x4)0.f;

    // A: row = s0 + mw*64 + mt*16 + l15 ; k = kc*32 + quad*8 + j
    const float* aptr = enc + ((size_t)(b * SS + s0 + mw * 64 + l15)) * HH + quad * 8;

    const uint4* wg = (const uint4*)w2sw;   // chunk kc = uint4 [kc*1024, +1024)
    uint4 st[4];
#pragma unroll
    for (int i = 0; i < 4; ++i) st[i] = wg[t * 4 + i];
#pragma unroll
    for (int i = 0; i < 4; ++i) ((uint4*)w2buf[0])[t * 4 + i] = st[i];
    __syncthreads();

    for (int kc = 0; kc < 8; ++kc) {
        const int cur = kc & 1;
        if (kc < 7) {
#pragma unroll
            for (int i = 0; i < 4; ++i)
                st[i] = wg[(kc + 1) * 1024 + t * 4 + i];
        }
        // A fragments: 2 float4 + cvt per m-tile
        bf16x8 af[4];
#pragma unroll
        for (int mt = 0; mt < 4; ++mt) {
            const float* p = aptr + (size_t)mt * 16 * HH + kc * 32;
            float4 x = *(const float4*)p;
            float4 y = *(const float4*)(p + 4);
            af[mt] = cvt8(x, y);
        }
        // MFMA: b_frag per n-tile, reused over 4 m-tiles
#pragma unroll
        for (int nt = 0; nt < 8; ++nt) {
            bf16x8 bf = *(const bf16x8*)&w2buf[cur][(size_t)((nw * 8 + nt) * 64 + lane) * 8];
#pragma unroll
            for (int mt = 0; mt < 4; ++mt)
                acc[mt][nt] = __builtin_amdgcn_mfma_f32_16x16x32_bf16(
                    af[mt], bf, acc[mt][nt], 0, 0, 0);
        }
        if (kc < 7) {
#pragma unroll
            for (int i = 0; i < 4; ++i)
                ((uint4*)w2buf[cur ^ 1])[t * 4 + i] = st[i];
            __syncthreads();
        }
    }

    // Epilogue: energy = tanh(qq + k); per-lane V-dot over its 8 n-tiles,
    // reduce across the 16 lanes of each quad, combine nw halves via LDS.
    const float vb = V_b[0];
    float qv[8], vv[8];
#pragma unroll
    for (int nt = 0; nt < 8; ++nt) {
        const int n = nw * 128 + nt * 16 + l15;
        qv[nt] = qq[b * HH + n];
        vv[nt] = V_w[n];
    }
    float red[4][4];
#pragma unroll
    for (int mt = 0; mt < 4; ++mt) {
#pragma unroll
        for (int r = 0; r < 4; ++r) {
            float p = 0.f;
#pragma unroll
            for (int nt = 0; nt < 8; ++nt)
                p = fmaf(vv[nt], tanhf(qv[nt] + acc[mt][nt][r]), p);
#pragma unroll
            for (int off = 8; off > 0; off >>= 1)
                p += __shfl_down(p, off, 16);
            red[mt][r] = p;   // valid on l15 == 0
        }
    }
    if (nw == 0 && l15 == 0) {
#pragma unroll
        for (int mt = 0; mt < 4; ++mt)
#pragma unroll
            for (int r = 0; r < 4; ++r)
                scbuf[mw * 64 + mt * 16 + quad * 4 + r] = red[mt][r];
    }
    __syncthreads();
    if (nw == 1 && l15 == 0) {
#pragma unroll
        for (int mt = 0; mt < 4; ++mt)
#pragma unroll
            for (int r = 0; r < 4; ++r) {
                const int row = mw * 64 + mt * 16 + quad * 4 + r;
                scores[b * SS + s0 + row] = scbuf[row] + red[mt][r] + vb;
            }
    }
}

// ---------------------------------------------------------------------------
// Softmax stats per b: m = max, l = sum exp(score - m)
// ---------------------------------------------------------------------------
__global__ void stats_kernel(const float* __restrict__ scores,
                             float* __restrict__ stats) {
    __shared__ float red[256];
    const int b = blockIdx.x;
    const int t = threadIdx.x;
    float m = -INFINITY;
    for (int s = t; s < SS; s += 256) m = fmaxf(m, scores[b * SS + s]);
    red[t] = m;
    __syncthreads();
    for (int off = 128; off > 0; off >>= 1) {
        if (t < off) red[t] = fmaxf(red[t], red[t + off]);
        __syncthreads();
    }
    m = red[0];
    __syncthreads();
    float l = 0.f;
    for (int s = t; s < SS; s += 256) l += expf(scores[b * SS + s] - m);
    red[t] = l;
    __syncthreads();
    for (int off = 128; off > 0; off >>= 1) {
        if (t < off) red[t] += red[t + off];
        __syncthreads();
    }
    if (t == 0) {
        stats[b] = m;
        stats[BB + b] = red[0];
    }
}

// ---------------------------------------------------------------------------
// Weights (d_out) + partial context per (b, 64-row chunk). grid (64, BB).
// ---------------------------------------------------------------------------
__global__ __launch_bounds__(256)
void ctx_kernel(const float* __restrict__ scores,
                const float* __restrict__ stats,
                const float* __restrict__ enc,
                float* __restrict__ weights_out,
                float* __restrict__ part) {
    __shared__ float w[64];
    const int b = blockIdx.y;
    const int chunk = blockIdx.x;
    const int t = threadIdx.x;
    const int s0 = chunk * 64;

    const float m = stats[b];
    const float linv = 1.f / stats[BB + b];
    if (t < 64) {
        const float wv = expf(scores[b * SS + s0 + t] - m) * linv;
        weights_out[b * SS + s0 + t] = wv;
        w[t] = wv;
    }
    __syncthreads();

    float acc = 0.f;
    const float* ep = enc + (size_t)(b * SS + s0) * HH + t;
#pragma unroll 8
    for (int j = 0; j < 64; ++j)
        acc = fmaf(w[j], ep[(size_t)j * HH], acc);
    part[(size_t)(b * 64 + chunk) * HH + t] = acc;
}

// ---------------------------------------------------------------------------
// Reduce 64 partials -> context
// ---------------------------------------------------------------------------
__global__ void reduce_kernel(const float* __restrict__ part,
                              float* __restrict__ ctx_out) {
    const int b = blockIdx.x;
    const int h = threadIdx.x;
    float a = 0.f;
#pragma unroll
    for (int c = 0; c < 64; ++c) a += part[(size_t)(b * 64 + c) * HH + h];
    ctx_out[b * HH + h] = a;
}

// ---------------------------------------------------------------------------
extern "C" void kernel_launch(void* const* d_in, const int* in_sizes, int n_in,
                              void* d_out, int out_size, void* d_ws, size_t ws_size,
                              hipStream_t stream) {
    const float* hidden = (const float*)d_in[0];
    const float* enc    = (const float*)d_in[1];
    const float* W1_w   = (const float*)d_in[2];
    const float* W1_b   = (const float*)d_in[3];
    const float* W2_w   = (const float*)d_in[4];
    const float* W2_b   = (const float*)d_in[5];
    const float* V_w    = (const float*)d_in[6];
    const float* V_b    = (const float*)d_in[7];

    float* out_weights = (float*)d_out;                 // B*S
    float* out_ctx     = (float*)d_out + BB * SS;       // B*H

    float* ws      = (float*)d_ws;
    float* ws_qq   = ws;                                 // 8192
    float* ws_sc   = ws_qq + BB * HH;                    // 131072
    float* ws_st   = ws_sc + BB * SS;                    // 64
    float* ws_part = ws_st + 2 * BB;                     // 32*64*256 = 524288
    ushort* ws_w2  = (ushort*)(ws_part + BB * 64 * HH);  // 65536 bf16 (128 KB)

    w2_swizzle_kernel<<<dim3(256), dim3(256), 0, stream>>>(W2_w, ws_w2);
    qq_kernel<<<dim3(BB), dim3(HH), 0, stream>>>(hidden, W1_w, W1_b, W2_b, ws_qq);
    score_mfma_kernel<<<dim3(SS / 128, BB), dim3(256), 0, stream>>>(
        enc, ws_w2, ws_qq, V_w, V_b, ws_sc);
    stats_kernel<<<dim3(BB), dim3(256), 0, stream>>>(ws_sc, ws_st);
    ctx_kernel<<<dim3(64, BB), dim3(256), 0, stream>>>(
        ws_sc, ws_st, enc, out_weights, ws_part);
    reduce_kernel<<<dim3(BB), dim3(HH), 0, stream>>>(ws_part, out_ctx);
}

// Round 3
// 254.903 us; speedup vs baseline: 1.7425x; 1.3646x over previous
//
#include <hip/hip_runtime.h>
#include <hip/hip_bf16.h>
#include <math.h>

#define BB 32
#define SS 4096
#define HH 256

typedef __bf16 bf16x8 __attribute__((ext_vector_type(8)));
typedef float f32x4 __attribute__((ext_vector_type(4)));

#define GLOBAL_AS __attribute__((address_space(1)))
#define LDS_AS    __attribute__((address_space(3)))

__device__ inline bf16x8 cvt8(const float4& x, const float4& y) {
    union { __hip_bfloat162 p[4]; bf16x8 v; } u;
    u.p[0] = __float22bfloat162_rn(make_float2(x.x, x.y));
    u.p[1] = __float22bfloat162_rn(make_float2(x.z, x.w));
    u.p[2] = __float22bfloat162_rn(make_float2(y.x, y.y));
    u.p[3] = __float22bfloat162_rn(make_float2(y.z, y.w));
    return u.v;
}

// tanh via exp2-path: ~6 VALU ops vs ~25 for libm tanhf. |err| ~1e-7 rel.
__device__ inline float fast_tanh(float x) {
    float xc = fminf(fmaxf(x, -10.f), 10.f);
    float e  = __expf(2.f * xc);                       // e^{2x}, finite (<= e^20)
    return (e - 1.f) * __builtin_amdgcn_rcpf(e + 1.f); // (e-1)/(e+1)
}

// ---------------------------------------------------------------------------
// Prep (fused): blocks 0..255 swizzle W2 -> bf16 MFMA-B order;
// blocks 256..287 compute qq[b][h] = hidden[b]@W1[:,h] + W1_b[h] + W2_b[h].
// w2sw[((kc*16+nt)*64+lane)*8+j] = W2[kc*32+(lane>>4)*8+j][nt*16+(lane&15)]
// ---------------------------------------------------------------------------
__global__ void prep_kernel(const float* __restrict__ W2_w,
                            ushort* __restrict__ w2sw,
                            const float* __restrict__ hidden,
                            const float* __restrict__ W1_w,
                            const float* __restrict__ W1_b,
                            const float* __restrict__ W2_b,
                            float* __restrict__ qq) {
    __shared__ float hid[HH];
    const int t = threadIdx.x;
    if (blockIdx.x < 256) {
        const int i = blockIdx.x * 256 + t;
        const int j    = i & 7;
        const int lane = (i >> 3) & 63;
        const int nt   = (i >> 9) & 15;
        const int kc   = i >> 13;
        const int k = kc * 32 + ((lane >> 4) & 3) * 8 + j;
        const int n = nt * 16 + (lane & 15);
        __hip_bfloat16 h = __float2bfloat16(W2_w[k * HH + n]);
        w2sw[i] = *(ushort*)&h;
    } else {
        const int b = blockIdx.x - 256;
        hid[t] = hidden[b * HH + t];
        __syncthreads();
        float acc = 0.f;
#pragma unroll 16
        for (int k = 0; k < HH; ++k)
            acc = fmaf(hid[k], W1_w[k * HH + t], acc);
        qq[b * HH + t] = acc + W1_b[t] + W2_b[t];
    }
}

// ---------------------------------------------------------------------------
// Score kernel: grid (SS/64, BB), block 256 = 4 waves.
// Block tile: 64 s-rows x 256 h. Wave w owns rows [w*16, w*16+16), all 256 n.
// acc = 16 n-tiles x f32x4 = 64 regs/lane -> 4 waves/SIMD occupancy.
// W2 chunks (K=32) double-buffered in LDS via global_load_lds width 16.
// Emits scores + per-block (max, sum-exp) softmax partials.
// ---------------------------------------------------------------------------
__global__ __launch_bounds__(256, 4)
void score64_kernel(const float* __restrict__ enc,
                    const ushort* __restrict__ w2sw,
                    const float* __restrict__ qq,
                    const float* __restrict__ V_w,
                    const float* __restrict__ V_b,
                    float* __restrict__ scores,
                    float* __restrict__ mlpart) {
    __shared__ ushort w2buf[2][8192];   // 2 x 16 KB
    __shared__ float sc_lds[64];

    const int t    = threadIdx.x;
    const int b    = blockIdx.y;
    const int s0   = blockIdx.x * 64;
    const int wave = t >> 6;
    const int lane = t & 63;
    const int l15  = lane & 15;
    const int quad = lane >> 4;

    f32x4 acc[16];
#pragma unroll
    for (int nt = 0; nt < 16; ++nt) acc[nt] = (f32x4)0.f;

    // issue W2 chunk 0 -> buf0 (4 sweeps of 4 KB; dest = wave base + lane*16)
    {
        const char* gsrc = (const char*)w2sw + t * 16;
        char* ldst = (char*)&w2buf[0][0] + wave * 1024;
#pragma unroll
        for (int i = 0; i < 4; ++i)
            __builtin_amdgcn_global_load_lds(
                (const GLOBAL_AS void*)(gsrc + i * 4096),
                (LDS_AS void*)(ldst + i * 4096), 16, 0, 0);
    }

    // A fragment pointer: row = s0 + wave*16 + l15, k = kc*32 + quad*8 + j
    const float* aptr =
        enc + ((size_t)(b * SS + s0 + wave * 16 + l15)) * HH + quad * 8;
    float4 ax = *(const float4*)aptr;
    float4 ay = *(const float4*)(aptr + 4);

    for (int kc = 0; kc < 8; ++kc) {
        const int cur = kc & 1;
        __syncthreads();   // drains vmcnt: chunk kc resident, prefetched A in regs
        if (kc < 7) {
            const char* gsrc = (const char*)w2sw + (kc + 1) * 16384 + t * 16;
            char* ldst = (char*)&w2buf[cur ^ 1][0] + wave * 1024;
#pragma unroll
            for (int i = 0; i < 4; ++i)
                __builtin_amdgcn_global_load_lds(
                    (const GLOBAL_AS void*)(gsrc + i * 4096),
                    (LDS_AS void*)(ldst + i * 4096), 16, 0, 0);
        }
        bf16x8 af = cvt8(ax, ay);
        if (kc < 7) {
            ax = *(const float4*)(aptr + (kc + 1) * 32);
            ay = *(const float4*)(aptr + (kc + 1) * 32 + 4);
        }
#pragma unroll
        for (int nt = 0; nt < 16; ++nt) {
            bf16x8 bf = *(const bf16x8*)&w2buf[cur][(nt * 64 + lane) * 8];
            acc[nt] = __builtin_amdgcn_mfma_f32_16x16x32_bf16(af, bf, acc[nt], 0, 0, 0);
        }
    }

    // Epilogue: score rows. C layout: col = l15, row(local) = quad*4 + r.
    float p[4] = {0.f, 0.f, 0.f, 0.f};
#pragma unroll
    for (int nt = 0; nt < 16; ++nt) {
        const int n = nt * 16 + l15;
        const float qn = qq[b * HH + n];
        const float vn = V_w[n];
#pragma unroll
        for (int r = 0; r < 4; ++r)
            p[r] = fmaf(vn, fast_tanh(qn + acc[nt][r]), p[r]);
    }
#pragma unroll
    for (int off = 1; off < 16; off <<= 1)
#pragma unroll
        for (int r = 0; r < 4; ++r)
            p[r] += __shfl_xor(p[r], off);

    const float vb = V_b[0];
    if (l15 == 0) {
        float4 pv = make_float4(p[0] + vb, p[1] + vb, p[2] + vb, p[3] + vb);
        const int row = wave * 16 + quad * 4;
        *(float4*)&sc_lds[row] = pv;
        *(float4*)&scores[b * SS + s0 + row] = pv;
    }
    __syncthreads();

    // per-block softmax partial (m, l) from the 64 scores (wave 0)
    if (t < 64) {
        const float v = sc_lds[t];
        float m = v;
#pragma unroll
        for (int off = 1; off < 64; off <<= 1)
            m = fmaxf(m, __shfl_xor(m, off));
        float e = __expf(v - m);
#pragma unroll
        for (int off = 1; off < 64; off <<= 1)
            e += __shfl_xor(e, off);
        if (t == 0) {
            mlpart[(b * 64 + blockIdx.x) * 2]     = m;
            mlpart[(b * 64 + blockIdx.x) * 2 + 1] = e;
        }
    }
}

// ---------------------------------------------------------------------------
// ctx kernel: grid (32, BB), block 256. Chunk = 128 s-rows.
// Merges the 64 (m,l) partials in-register, writes weights (d_out),
// accumulates partial context with float4 loads, folds to 1 slot per chunk.
// ---------------------------------------------------------------------------
__global__ __launch_bounds__(256)
void ctx_kernel(const float* __restrict__ scores,
                const float* __restrict__ mlpart,
                const float* __restrict__ enc,
                float* __restrict__ weights_out,
                float* __restrict__ part) {
    __shared__ float wlds[128];
    __shared__ float accl[4][HH];
    __shared__ float mg_s, linv_s;

    const int t  = threadIdx.x;
    const int b  = blockIdx.y;
    const int c  = blockIdx.x;
    const int s0 = c * 128;

    if (t < 64) {
        const float2 ml = ((const float2*)mlpart)[b * 64 + t];
        float m = ml.x;
#pragma unroll
        for (int off = 1; off < 64; off <<= 1)
            m = fmaxf(m, __shfl_xor(m, off));
        float l = ml.y * __expf(ml.x - m);
#pragma unroll
        for (int off = 1; off < 64; off <<= 1)
            l += __shfl_xor(l, off);
        if (t == 0) { mg_s = m; linv_s = 1.f / l; }
    }
    __syncthreads();
    const float mg = mg_s, linv = linv_s;

    if (t < 128) {
        const float w = __expf(scores[b * SS + s0 + t] - mg) * linv;
        weights_out[b * SS + s0 + t] = w;
        wlds[t] = w;
    }
    __syncthreads();

    // thread (tr = t>>6, tc = t&63): cols h0 = tc*4, rows j = jj*4 + tr
    const int tr = t >> 6;
    const int h0 = (t & 63) * 4;
    float4 a = make_float4(0.f, 0.f, 0.f, 0.f);
    const float* ep = enc + ((size_t)(b * SS + s0)) * HH;
#pragma unroll 8
    for (int jj = 0; jj < 32; ++jj) {
        const int j = jj * 4 + tr;
        const float4 e = *(const float4*)(ep + (size_t)j * HH + h0);
        const float w = wlds[j];
        a.x = fmaf(w, e.x, a.x);
        a.y = fmaf(w, e.y, a.y);
        a.z = fmaf(w, e.z, a.z);
        a.w = fmaf(w, e.w, a.w);
    }
    *(float4*)&accl[tr][h0] = a;
    __syncthreads();

    const float s = accl[0][t] + accl[1][t] + accl[2][t] + accl[3][t];
    part[((size_t)(b * 32 + c)) * HH + t] = s;
}

// ---------------------------------------------------------------------------
// Reduce 32 partials -> context
// ---------------------------------------------------------------------------
__global__ void reduce_kernel(const float* __restrict__ part,
                              float* __restrict__ ctx_out) {
    const int b = blockIdx.x;
    const int h = threadIdx.x;
    float a = 0.f;
#pragma unroll 8
    for (int c = 0; c < 32; ++c) a += part[((size_t)(b * 32 + c)) * HH + h];
    ctx_out[b * HH + h] = a;
}

// ---------------------------------------------------------------------------
extern "C" void kernel_launch(void* const* d_in, const int* in_sizes, int n_in,
                              void* d_out, int out_size, void* d_ws, size_t ws_size,
                              hipStream_t stream) {
    const float* hidden = (const float*)d_in[0];
    const float* enc    = (const float*)d_in[1];
    const float* W1_w   = (const float*)d_in[2];
    const float* W1_b   = (const float*)d_in[3];
    const float* W2_w   = (const float*)d_in[4];
    const float* W2_b   = (const float*)d_in[5];
    const float* V_w    = (const float*)d_in[6];
    const float* V_b    = (const float*)d_in[7];

    float* out_weights = (float*)d_out;                 // B*S
    float* out_ctx     = (float*)d_out + BB * SS;       // B*H

    float* ws      = (float*)d_ws;
    float* ws_qq   = ws;                                 // 8192
    float* ws_sc   = ws_qq + BB * HH;                    // 131072
    float* ws_ml   = ws_sc + BB * SS;                    // 32*64*2 = 4096
    float* ws_part = ws_ml + BB * 64 * 2;                // 32*32*256 = 262144
    ushort* ws_w2  = (ushort*)(ws_part + BB * 32 * HH);  // 65536 bf16 (128 KB)

    prep_kernel<<<dim3(256 + BB), dim3(256), 0, stream>>>(
        W2_w, ws_w2, hidden, W1_w, W1_b, W2_b, ws_qq);
    score64_kernel<<<dim3(SS / 64, BB), dim3(256), 0, stream>>>(
        enc, ws_w2, ws_qq, V_w, V_b, ws_sc, ws_ml);
    ctx_kernel<<<dim3(32, BB), dim3(256), 0, stream>>>(
        ws_sc, ws_ml, enc, out_weights, ws_part);
    reduce_kernel<<<dim3(BB), dim3(HH), 0, stream>>>(ws_part, out_ctx);
}